// Round 7
// baseline (111.716 us; speedup 1.0000x reference)
//
#include <hip/hip_runtime.h>

#define HID 256
#define NB 8
#define SQL 2048
#define SKV 2048
#define SPLIT 4
#define KPB (SKV / SPLIT)   // 512 keys per (b,split) stream
#define KVB 32              // keys per staged tile
#define NT (KPB / KVB)      // 16 steps
#define NROW (NB * SQL)     // 16384 rows

typedef __attribute__((ext_vector_type(8))) short bf16x8;
typedef __attribute__((ext_vector_type(4))) float f32x4;

static __device__ __forceinline__ unsigned short f2bf(float x) {
  union { float f; unsigned int u; } v; v.f = x;
  unsigned int r = v.u + 0x7FFFu + ((v.u >> 16) & 1u);
  return (unsigned short)(r >> 16);
}

// ---------- P0: convert weight matrices to bf16 ----------
__global__ void wconv_kernel(const float* __restrict__ Wq, const float* __restrict__ Wk,
                             const float* __restrict__ Wv, unsigned short* __restrict__ out) {
  int i = blockIdx.x * blockDim.x + threadIdx.x;
  if (i >= 3 * HID * HID) return;
  const float* src = (i < HID * HID) ? Wq : (i < 2 * HID * HID ? Wk : Wv);
  out[i] = f2bf(src[i & (HID * HID - 1)]);
}

// ---------- P1: QKV projection; W-half staged in LDS (swizzled) ----------
__global__ __launch_bounds__(512, 4) void proj_kernel(
    const float* __restrict__ query, const float* __restrict__ key, const float* __restrict__ value,
    const unsigned short* __restrict__ Wb,
    const float* __restrict__ bq, const float* __restrict__ bk, const float* __restrict__ bv,
    unsigned short* __restrict__ Qb, unsigned short* __restrict__ Kb, unsigned short* __restrict__ Vtb) {
  __shared__ __align__(16) char wl[65536];
  int tid = threadIdx.x;
  int wave = tid >> 6, lane = tid & 63, lr = lane & 15, lg = lane >> 4;
  int blk = blockIdx.x;
  int mat = blk >> 8;       // 0:Q 1:K 2:V
  int rem = blk & 255;
  int b = rem >> 5;
  int rt = (rem >> 1) & 15;
  int et = rem & 1;

  const float* X = (mat == 0) ? query : (mat == 1 ? key : value);
  const float* bias = (mat == 0) ? bq : (mat == 1 ? bk : bv);
  const char* Wsrc = (const char*)(Wb + mat * HID * HID + et * 128 * HID);

#pragma unroll
  for (int i = 0; i < 8; i++) {
    int c = i * 512 + tid;
    int e = c >> 5;
    int glo = e * 512 + (((c & 31) ^ (e & 7)) << 4);
    __builtin_amdgcn_global_load_lds(
        (const __attribute__((address_space(1))) unsigned int*)(Wsrc + glo),
        (__attribute__((address_space(3))) unsigned int*)(wl + c * 16), 16, 0, 0);
  }

  int row_a = rt * 128 + wave * 16 + lr;
  const float* xrow = X + ((size_t)(b * SQL + row_a)) * HID;
  bf16x8 af[8];
#pragma unroll
  for (int s = 0; s < 8; s++) {
    const float4* p = (const float4*)(xrow + s * 32 + lg * 8);
    float4 x0 = p[0], x1 = p[1];
    bf16x8 a;
    a[0] = (short)f2bf(x0.x); a[1] = (short)f2bf(x0.y); a[2] = (short)f2bf(x0.z); a[3] = (short)f2bf(x0.w);
    a[4] = (short)f2bf(x1.x); a[5] = (short)f2bf(x1.y); a[6] = (short)f2bf(x1.z); a[7] = (short)f2bf(x1.w);
    af[s] = a;
  }
  __syncthreads();

  int row_c = rt * 128 + wave * 16 + lg * 4;
#pragma unroll
  for (int eo = 0; eo < 8; eo++) {
    f32x4 acc = (f32x4){0.f, 0.f, 0.f, 0.f};
    int eL = eo * 16 + lr;
#pragma unroll
    for (int sl = 0; sl < 8; sl++) {
      bf16x8 bfr = *(const bf16x8*)(wl + eL * 512 + (((sl * 4 + lg) ^ (eL & 7)) << 4));
      acc = __builtin_amdgcn_mfma_f32_16x16x32_bf16(af[sl], bfr, acc, 0, 0, 0);
    }
    int e = et * 128 + eo * 16 + lr;
    float bv_ = bias[e];
    if (mat < 2) {
      unsigned short* dst = (mat == 0 ? Qb : Kb) + (size_t)(b * SQL) * HID;
#pragma unroll
      for (int i = 0; i < 4; i++)
        dst[(size_t)(row_c + i) * HID + e] = f2bf(acc[i] + bv_);
    } else {
      ushort4 v;
      v.x = f2bf(acc[0] + bv_); v.y = f2bf(acc[1] + bv_);
      v.z = f2bf(acc[2] + bv_); v.w = f2bf(acc[3] + bv_);
      *(ushort4*)(Vtb + ((size_t)(b * HID + e)) * SKV + row_c) = v;
    }
  }
}

// ---------- A: flash attention, 16q/wave, 4 waves/SIMD, sigma-permuted K ----------
__global__ __launch_bounds__(512, 4) void attn_kernel(
    const unsigned short* __restrict__ Qb, const unsigned short* __restrict__ Kb,
    const unsigned short* __restrict__ Vtb, unsigned short* __restrict__ Op,
    float* __restrict__ Ml) {
  __shared__ __align__(16) char smem[65536];  // K0[16K] K1[16K] V0[16K] V1[16K]
  int tid = threadIdx.x;
  int wave = tid >> 6, lane = tid & 63, l15 = lane & 15, g = lane >> 4;
  int L = (blockIdx.x & 7) * 64 + (blockIdx.x >> 3);  // XCD x owns batch x
  int b = L >> 6, sp = (L >> 4) & 3, qt = L & 15;
  int q0 = qt * 128 + wave * 16;

  const char* Kc0 = (const char*)(Kb + ((size_t)b * SKV + (size_t)sp * KPB) * HID);
  const char* Vc0 = (const char*)(Vtb + (size_t)b * HID * SKV + (size_t)sp * KPB);

  // staging source offsets. K rows stored sigma-permuted + chunk-XOR-swizzled:
  //   LDS row r holds global key sig(r) = 8*((r&15)>>2) + (r&3) + 4*(r>>4)
  //   LDS slot cs of row r holds chunk c = cs ^ r
  int offK[2], offV[2];
#pragma unroll
  for (int i = 0; i < 2; i++) {
    int g2 = i * 512 + tid;           // 0..1023
    int r = g2 >> 5, cs = g2 & 31;
    int sig = 8 * ((r & 15) >> 2) + (r & 3) + 4 * (r >> 4);
    offK[i] = sig * 512 + ((cs ^ r) << 4);
    int d = g2 >> 2, kc = g2 & 3;
    offV[i] = d * (SKV * 2) + kc * 16;
  }

  auto stage = [&](int t, char* kb, char* vb) {
    const char* Ks = Kc0 + t * (KVB * HID * 2);
    const char* Vs = Vc0 + t * (KVB * 2);
#pragma unroll
    for (int i = 0; i < 2; i++)
      __builtin_amdgcn_global_load_lds(
          (const __attribute__((address_space(1))) unsigned int*)(Ks + offK[i]),
          (__attribute__((address_space(3))) unsigned int*)(kb + (i * 512 + tid) * 16),
          16, 0, 0);
#pragma unroll
    for (int i = 0; i < 2; i++)
      __builtin_amdgcn_global_load_lds(
          (const __attribute__((address_space(1))) unsigned int*)(Vs + offV[i]),
          (__attribute__((address_space(3))) unsigned int*)(vb + (i * 512 + tid) * 16),
          16, 0, 0);
  };

  // Q fragments (B-operand): lane(q=l15, g) holds Q[q][s*32 + g*8 ..+7]
  bf16x8 qf[8];
  {
    const unsigned short* qrow = Qb + ((size_t)(b * SQL + q0 + l15)) * HID + g * 8;
#pragma unroll
    for (int s = 0; s < 8; s++) qf[s] = *(const bf16x8*)(qrow + s * 32);
  }

  f32x4 acc[16];  // C[row=d_local=g*4+i][col=q=l15] per d-tile
#pragma unroll
  for (int dt = 0; dt < 16; dt++) acc[dt] = (f32x4){0.f, 0.f, 0.f, 0.f};
  float m = -1e30f, lsum = 0.f;
  const float kC = 1.44269504088896341f / 11.3137084989847604f;  // log2(e)/sqrt(128)

  auto step = [&](const char* kb, const char* vb) {
    // QK^T swapped: p0 rows = LDS K rows 0-15 (keys 8g..8g+3), p1 rows 16-31 (keys 8g+4..+7)
    f32x4 p0 = (f32x4){0.f, 0.f, 0.f, 0.f}, p1 = (f32x4){0.f, 0.f, 0.f, 0.f};
#pragma unroll
    for (int s = 0; s < 8; s++) {
      int c0 = s * 4 + g;
      bf16x8 kf0 = *(const bf16x8*)(kb + l15 * 512 + ((c0 ^ l15) << 4));
      bf16x8 kf1 = *(const bf16x8*)(kb + (16 + l15) * 512 + (((c0 ^ l15) ^ 16) << 4));
      p0 = __builtin_amdgcn_mfma_f32_16x16x32_bf16(kf0, qf[s], p0, 0, 0, 0);
      p1 = __builtin_amdgcn_mfma_f32_16x16x32_bf16(kf1, qf[s], p1, 0, 0, 0);
    }

    // online softmax for q=l15 (8 local keys; reduce across 4 g-groups)
    float tmax = fmaxf(fmaxf(fmaxf(p0[0], p0[1]), fmaxf(p0[2], p0[3])),
                       fmaxf(fmaxf(p1[0], p1[1]), fmaxf(p1[2], p1[3])));
    tmax = fmaxf(tmax, __shfl_xor(tmax, 16, 64));
    tmax = fmaxf(tmax, __shfl_xor(tmax, 32, 64));
    float msc = tmax * kC;
    if (!__all(msc <= m + 8.0f)) {     // defer-max THR=8
      float mn = fmaxf(m, msc);
      float al = exp2f(m - mn);
      lsum *= al;
      m = mn;
#pragma unroll
      for (int dt = 0; dt < 16; dt++)  // acc cols are q: al is lane-local
#pragma unroll
        for (int i = 0; i < 4; i++) acc[dt][i] *= al;
    }
#pragma unroll
    for (int i = 0; i < 4; i++) {
      p0[i] = exp2f(fmaf(p0[i], kC, -m));
      p1[i] = exp2f(fmaf(p1[i], kC, -m));
    }
    float ts = (p0[0] + p0[1]) + (p0[2] + p0[3]) + (p1[0] + p1[1]) + (p1[2] + p1[3]);
    ts += __shfl_xor(ts, 16, 64);
    ts += __shfl_xor(ts, 32, 64);
    lsum += ts;

    // P -> PV B-fragment directly (keys 8g..8g+7 already lane-local)
    unsigned w0, w1, w2, w3;
    asm("v_cvt_pk_bf16_f32 %0, %1, %2" : "=v"(w0) : "v"(p0[0]), "v"(p0[1]));
    asm("v_cvt_pk_bf16_f32 %0, %1, %2" : "=v"(w1) : "v"(p0[2]), "v"(p0[3]));
    asm("v_cvt_pk_bf16_f32 %0, %1, %2" : "=v"(w2) : "v"(p1[0]), "v"(p1[1]));
    asm("v_cvt_pk_bf16_f32 %0, %1, %2" : "=v"(w3) : "v"(p1[2]), "v"(p1[3]));
    union { unsigned u[4]; bf16x8 v; } pa;
    pa.u[0] = w0; pa.u[1] = w1; pa.u[2] = w2; pa.u[3] = w3;

    // PV swapped: C[row=d][col=q]; A = Vt[d][k0..k0+31]
#pragma unroll
    for (int dt = 0; dt < 16; dt++) {
      bf16x8 vf = *(const bf16x8*)(vb + dt * 1024 + l15 * 64 + g * 16);
      acc[dt] = __builtin_amdgcn_mfma_f32_16x16x32_bf16(vf, pa.v, acc[dt], 0, 0, 0);
    }
  };

  stage(0, smem, smem + 32768);
  __syncthreads();
  for (int t = 0; t < NT; t++) {
    char* kb = smem + (t & 1) * 16384;
    char* vb = smem + 32768 + (t & 1) * 16384;
    if (t + 1 < NT)
      stage(t + 1, smem + ((t + 1) & 1) * 16384, smem + 32768 + ((t + 1) & 1) * 16384);
    step(kb, vb);
    __syncthreads();  // drain lands after compute: prefetch overlapped
  }

  // epilogue: (m,l) per q lane-local; acc cols = q, rows = d
  size_t rowq = (size_t)b * SQL + q0 + l15;
  if (g == 0) {
    float2 ml; ml.x = m; ml.y = lsum;
    *(float2*)(Ml + ((size_t)sp * NROW + rowq) * 2) = ml;
  }
  float linv = 1.0f / lsum;
  unsigned short* orow = Op + ((size_t)sp * NROW + rowq) * HID;
#pragma unroll
  for (int dt = 0; dt < 16; dt++) {
    ushort4 v;
    union { _Float16 hf; unsigned short u; } c0, c1, c2, c3;
    c0.hf = (_Float16)(acc[dt][0] * linv); c1.hf = (_Float16)(acc[dt][1] * linv);
    c2.hf = (_Float16)(acc[dt][2] * linv); c3.hf = (_Float16)(acc[dt][3] * linv);
    v.x = c0.u; v.y = c1.u; v.z = c2.u; v.w = c3.u;
    *(ushort4*)(orow + dt * 16 + g * 4) = v;
  }
}

// ---------- C: combine split partials ----------
__global__ __launch_bounds__(256) void comb_kernel(const unsigned short* __restrict__ Op,
                                                   const float* __restrict__ Ml,
                                                   float* __restrict__ out) {
  int idx = blockIdx.x * 256 + threadIdx.x;
  int row = idx >> 6;
  int d0 = (idx & 63) << 2;
  float mv[SPLIT], lv[SPLIT];
#pragma unroll
  for (int s = 0; s < SPLIT; s++) {
    float2 ml = *(const float2*)(Ml + ((size_t)s * NROW + row) * 2);
    mv[s] = ml.x; lv[s] = ml.y;
  }
  float M = mv[0];
#pragma unroll
  for (int s = 1; s < SPLIT; s++) M = fmaxf(M, mv[s]);
  float W = 0.f, w[SPLIT];
#pragma unroll
  for (int s = 0; s < SPLIT; s++) { w[s] = lv[s] * exp2f(mv[s] - M); W += w[s]; }
  float wi = 1.0f / W;
  float o0 = 0.f, o1 = 0.f, o2 = 0.f, o3 = 0.f;
#pragma unroll
  for (int s = 0; s < SPLIT; s++) {
    ushort4 u = *(const ushort4*)(Op + ((size_t)s * NROW + row) * HID + d0);
    union { unsigned short us; _Float16 hf; } c0, c1, c2, c3;
    c0.us = u.x; c1.us = u.y; c2.us = u.z; c3.us = u.w;
    o0 += w[s] * (float)c0.hf; o1 += w[s] * (float)c1.hf;
    o2 += w[s] * (float)c2.hf; o3 += w[s] * (float)c3.hf;
  }
  float4 res; res.x = o0 * wi; res.y = o1 * wi; res.z = o2 * wi; res.w = o3 * wi;
  *(float4*)(out + (size_t)row * HID + d0) = res;
}

extern "C" void kernel_launch(void* const* d_in, const int* in_sizes, int n_in,
                              void* d_out, int out_size, void* d_ws, size_t ws_size,
                              hipStream_t stream) {
  const float* query = (const float*)d_in[0];
  const float* key   = (const float*)d_in[1];
  const float* value = (const float*)d_in[2];
  const float* Wq = (const float*)d_in[3];
  const float* bq = (const float*)d_in[4];
  const float* Wk = (const float*)d_in[5];
  const float* bk = (const float*)d_in[6];
  const float* Wv = (const float*)d_in[7];
  const float* bv = (const float*)d_in[8];

  char* ws = (char*)d_ws;
  unsigned short* Wb  = (unsigned short*)ws;                        // 393216 B
  unsigned short* Qb  = (unsigned short*)(ws + 393216);
  unsigned short* Kb  = Qb + (size_t)NB * SQL * HID;
  unsigned short* Vtb = Kb + (size_t)NB * SKV * HID;                // [b][d][s]
  unsigned short* Op  = Vtb + (size_t)NB * HID * SKV;               // f16 partials
  float* Ml = (float*)(Op + (size_t)SPLIT * NROW * HID);            // (m,l)

  hipLaunchKernelGGL(wconv_kernel, dim3(768), dim3(256), 0, stream, Wq, Wk, Wv, Wb);
  hipLaunchKernelGGL(proj_kernel, dim3(768), dim3(512), 0, stream,
                     query, key, value, Wb, bq, bk, bv, Qb, Kb, Vtb);
  hipLaunchKernelGGL(attn_kernel, dim3(512), dim3(512), 0, stream, Qb, Kb, Vtb, Op, Ml);
  hipLaunchKernelGGL(comb_kernel, dim3(4096), dim3(256), 0, stream, Op, Ml, (float*)d_out);
}

// Round 8
// 103.820 us; speedup vs baseline: 1.0761x; 1.0761x over previous
//
#include <hip/hip_runtime.h>

#define HID 256
#define NB 8
#define SQL 2048
#define SKV 2048
#define SPLIT 4
#define KPB (SKV / SPLIT)   // 512 keys per (b,split) stream
#define KVB 32              // keys per staged tile
#define NT (KPB / KVB)      // 16 steps
#define NROW (NB * SQL)     // 16384 rows

typedef __attribute__((ext_vector_type(8))) short bf16x8;
typedef __attribute__((ext_vector_type(4))) float f32x4;

static __device__ __forceinline__ unsigned short f2bf(float x) {
  union { float f; unsigned int u; } v; v.f = x;
  unsigned int r = v.u + 0x7FFFu + ((v.u >> 16) & 1u);
  return (unsigned short)(r >> 16);
}

// ---------- P0: convert weight matrices to bf16 ----------
__global__ void wconv_kernel(const float* __restrict__ Wq, const float* __restrict__ Wk,
                             const float* __restrict__ Wv, unsigned short* __restrict__ out) {
  int i = blockIdx.x * blockDim.x + threadIdx.x;
  if (i >= 3 * HID * HID) return;
  const float* src = (i < HID * HID) ? Wq : (i < 2 * HID * HID ? Wk : Wv);
  out[i] = f2bf(src[i & (HID * HID - 1)]);
}

// ---------- P1: QKV projection; W-half staged in LDS (swizzled) ----------
__global__ __launch_bounds__(512, 4) void proj_kernel(
    const float* __restrict__ query, const float* __restrict__ key, const float* __restrict__ value,
    const unsigned short* __restrict__ Wb,
    const float* __restrict__ bq, const float* __restrict__ bk, const float* __restrict__ bv,
    unsigned short* __restrict__ Qb, unsigned short* __restrict__ Kb, unsigned short* __restrict__ Vtb) {
  __shared__ __align__(16) char wl[65536];
  int tid = threadIdx.x;
  int wave = tid >> 6, lane = tid & 63, lr = lane & 15, lg = lane >> 4;
  int blk = blockIdx.x;
  int mat = blk >> 8;       // 0:Q 1:K 2:V
  int rem = blk & 255;
  int b = rem >> 5;
  int rt = (rem >> 1) & 15;
  int et = rem & 1;

  const float* X = (mat == 0) ? query : (mat == 1 ? key : value);
  const float* bias = (mat == 0) ? bq : (mat == 1 ? bk : bv);
  const char* Wsrc = (const char*)(Wb + mat * HID * HID + et * 128 * HID);

#pragma unroll
  for (int i = 0; i < 8; i++) {
    int c = i * 512 + tid;
    int e = c >> 5;
    int glo = e * 512 + (((c & 31) ^ (e & 7)) << 4);
    __builtin_amdgcn_global_load_lds(
        (const __attribute__((address_space(1))) unsigned int*)(Wsrc + glo),
        (__attribute__((address_space(3))) unsigned int*)(wl + c * 16), 16, 0, 0);
  }

  int row_a = rt * 128 + wave * 16 + lr;
  const float* xrow = X + ((size_t)(b * SQL + row_a)) * HID;
  bf16x8 af[8];
#pragma unroll
  for (int s = 0; s < 8; s++) {
    const float4* p = (const float4*)(xrow + s * 32 + lg * 8);
    float4 x0 = p[0], x1 = p[1];
    bf16x8 a;
    a[0] = (short)f2bf(x0.x); a[1] = (short)f2bf(x0.y); a[2] = (short)f2bf(x0.z); a[3] = (short)f2bf(x0.w);
    a[4] = (short)f2bf(x1.x); a[5] = (short)f2bf(x1.y); a[6] = (short)f2bf(x1.z); a[7] = (short)f2bf(x1.w);
    af[s] = a;
  }
  __syncthreads();

  int row_c = rt * 128 + wave * 16 + lg * 4;
#pragma unroll
  for (int eo = 0; eo < 8; eo++) {
    f32x4 acc = (f32x4){0.f, 0.f, 0.f, 0.f};
    int eL = eo * 16 + lr;
#pragma unroll
    for (int sl = 0; sl < 8; sl++) {
      bf16x8 bfr = *(const bf16x8*)(wl + eL * 512 + (((sl * 4 + lg) ^ (eL & 7)) << 4));
      acc = __builtin_amdgcn_mfma_f32_16x16x32_bf16(af[sl], bfr, acc, 0, 0, 0);
    }
    int e = et * 128 + eo * 16 + lr;
    float bv_ = bias[e];
    if (mat < 2) {
      unsigned short* dst = (mat == 0 ? Qb : Kb) + (size_t)(b * SQL) * HID;
#pragma unroll
      for (int i = 0; i < 4; i++)
        dst[(size_t)(row_c + i) * HID + e] = f2bf(acc[i] + bv_);
    } else {
      ushort4 v;
      v.x = f2bf(acc[0] + bv_); v.y = f2bf(acc[1] + bv_);
      v.z = f2bf(acc[2] + bv_); v.w = f2bf(acc[3] + bv_);
      *(ushort4*)(Vtb + ((size_t)(b * HID + e)) * SKV + row_c) = v;
    }
  }
}

// ---------- A: flash attention, 32q/wave (2 tiles), 4-wave blocks, 2 blocks/CU ----------
__global__ __launch_bounds__(256, 2) void attn_kernel(
    const unsigned short* __restrict__ Qb, const unsigned short* __restrict__ Kb,
    const unsigned short* __restrict__ Vtb, unsigned short* __restrict__ Op,
    float* __restrict__ Ml) {
  extern __shared__ char smem[];  // KA[16K] KB[16K] VA[16K] VB[16K]
  int tid = threadIdx.x;
  int wave = tid >> 6, lane = tid & 63, l15 = lane & 15, g = lane >> 4;
  int L = (blockIdx.x & 7) * 64 + (blockIdx.x >> 3);  // XCD x owns batch x
  int b = L >> 6, sp = (L >> 4) & 3, qt = L & 15;
  int q0 = qt * 128 + wave * 32;   // wave owns q0..q0+31 (2 tiles of 16)

  const char* Kc0 = (const char*)(Kb + ((size_t)b * SKV + (size_t)sp * KPB) * HID);
  const char* Vc0 = (const char*)(Vtb + (size_t)b * HID * SKV + (size_t)sp * KPB);

  // K LDS: row r holds key sig(r)=8*((r&15)>>2)+(r&3)+4*(r>>4); slot cs holds chunk cs^r.
  // V LDS: stripes of 128B hold d-pairs; slot p' of stripe r holds p=p'^(r&7),
  //        where p=(d&1)*4+c, d=2r+(p>>2), c=p&3.
  int offK[4], offV[4];
#pragma unroll
  for (int i = 0; i < 4; i++) {
    int idx = i * 256 + tid;          // 0..1023 (16B chunks)
    int r = idx >> 5, cs = idx & 31;
    int sig = 8 * ((r & 15) >> 2) + (r & 3) + 4 * (r >> 4);
    offK[i] = sig * 512 + ((cs ^ r) << 4);
    int rv = idx >> 3, pp = idx & 7;
    int p = pp ^ (rv & 7);
    int d = 2 * rv + (p >> 2), c = p & 3;
    offV[i] = d * (SKV * 2) + c * 16;
  }

  auto stage = [&](int t, char* kb, char* vb) {
    const char* Ks = Kc0 + t * (KVB * HID * 2);
    const char* Vs = Vc0 + t * (KVB * 2);
#pragma unroll
    for (int i = 0; i < 4; i++)
      __builtin_amdgcn_global_load_lds(
          (const __attribute__((address_space(1))) unsigned int*)(Ks + offK[i]),
          (__attribute__((address_space(3))) unsigned int*)(kb + (i * 256 + tid) * 16),
          16, 0, 0);
#pragma unroll
    for (int i = 0; i < 4; i++)
      __builtin_amdgcn_global_load_lds(
          (const __attribute__((address_space(1))) unsigned int*)(Vs + offV[i]),
          (__attribute__((address_space(3))) unsigned int*)(vb + (i * 256 + tid) * 16),
          16, 0, 0);
  };

  // Q fragments for both tiles: lane(q=l15,g) holds Q[q][s*32+g*8..+7]
  bf16x8 qfa[8], qfb[8];
  {
    const unsigned short* qa = Qb + ((size_t)(b * SQL + q0 + l15)) * HID + g * 8;
    const unsigned short* qb2 = qa + 16 * HID;
#pragma unroll
    for (int s = 0; s < 8; s++) {
      qfa[s] = *(const bf16x8*)(qa + s * 32);
      qfb[s] = *(const bf16x8*)(qb2 + s * 32);
    }
  }

  f32x4 acc0[16], acc1[16];  // C[row=d_local=g*4+i][col=q=l15] per d-tile, per q-tile
#pragma unroll
  for (int dt = 0; dt < 16; dt++) {
    acc0[dt] = (f32x4){0.f, 0.f, 0.f, 0.f};
    acc1[dt] = (f32x4){0.f, 0.f, 0.f, 0.f};
  }
  float m0 = -1e30f, l0 = 0.f, m1 = -1e30f, l1 = 0.f;
  const float kC = 1.44269504088896341f / 11.3137084989847604f;  // log2(e)/sqrt(128)

  auto step = [&](const char* kb, const char* vb) {
    // QK^T swapped, both q-tiles share every K-frag read
    f32x4 p0a = (f32x4){0.f,0.f,0.f,0.f}, p1a = (f32x4){0.f,0.f,0.f,0.f};
    f32x4 p0b = (f32x4){0.f,0.f,0.f,0.f}, p1b = (f32x4){0.f,0.f,0.f,0.f};
#pragma unroll
    for (int s = 0; s < 8; s++) {
      int c0 = s * 4 + g;
      bf16x8 kf0 = *(const bf16x8*)(kb + l15 * 512 + ((c0 ^ l15) << 4));
      bf16x8 kf1 = *(const bf16x8*)(kb + (16 + l15) * 512 + (((c0 ^ l15) ^ 16) << 4));
      p0a = __builtin_amdgcn_mfma_f32_16x16x32_bf16(kf0, qfa[s], p0a, 0, 0, 0);
      p1a = __builtin_amdgcn_mfma_f32_16x16x32_bf16(kf1, qfa[s], p1a, 0, 0, 0);
      p0b = __builtin_amdgcn_mfma_f32_16x16x32_bf16(kf0, qfb[s], p0b, 0, 0, 0);
      p1b = __builtin_amdgcn_mfma_f32_16x16x32_bf16(kf1, qfb[s], p1b, 0, 0, 0);
    }

    // two independent online softmaxes (q lane-local; keys 8g..8g+7 per lane via sigma)
    float ta = fmaxf(fmaxf(fmaxf(p0a[0], p0a[1]), fmaxf(p0a[2], p0a[3])),
                     fmaxf(fmaxf(p1a[0], p1a[1]), fmaxf(p1a[2], p1a[3])));
    float tb = fmaxf(fmaxf(fmaxf(p0b[0], p0b[1]), fmaxf(p0b[2], p0b[3])),
                     fmaxf(fmaxf(p1b[0], p1b[1]), fmaxf(p1b[2], p1b[3])));
    ta = fmaxf(ta, __shfl_xor(ta, 16, 64)); tb = fmaxf(tb, __shfl_xor(tb, 16, 64));
    ta = fmaxf(ta, __shfl_xor(ta, 32, 64)); tb = fmaxf(tb, __shfl_xor(tb, 32, 64));
    float msa = ta * kC, msb = tb * kC;
    if (!__all(msa <= m0 + 8.0f)) {
      float mn = fmaxf(m0, msa);
      float al = exp2f(m0 - mn);
      l0 *= al; m0 = mn;
#pragma unroll
      for (int dt = 0; dt < 16; dt++)
#pragma unroll
        for (int i = 0; i < 4; i++) acc0[dt][i] *= al;
    }
    if (!__all(msb <= m1 + 8.0f)) {
      float mn = fmaxf(m1, msb);
      float al = exp2f(m1 - mn);
      l1 *= al; m1 = mn;
#pragma unroll
      for (int dt = 0; dt < 16; dt++)
#pragma unroll
        for (int i = 0; i < 4; i++) acc1[dt][i] *= al;
    }
#pragma unroll
    for (int i = 0; i < 4; i++) {
      p0a[i] = exp2f(fmaf(p0a[i], kC, -m0)); p1a[i] = exp2f(fmaf(p1a[i], kC, -m0));
      p0b[i] = exp2f(fmaf(p0b[i], kC, -m1)); p1b[i] = exp2f(fmaf(p1b[i], kC, -m1));
    }
    float sa = (p0a[0] + p0a[1]) + (p0a[2] + p0a[3]) + (p1a[0] + p1a[1]) + (p1a[2] + p1a[3]);
    float sb = (p0b[0] + p0b[1]) + (p0b[2] + p0b[3]) + (p1b[0] + p1b[1]) + (p1b[2] + p1b[3]);
    sa += __shfl_xor(sa, 16, 64); sb += __shfl_xor(sb, 16, 64);
    sa += __shfl_xor(sa, 32, 64); sb += __shfl_xor(sb, 32, 64);
    l0 += sa; l1 += sb;

    // P -> PV B-fragments directly (keys already lane-local)
    unsigned wa0, wa1, wa2, wa3, wb0, wb1, wb2, wb3;
    asm("v_cvt_pk_bf16_f32 %0, %1, %2" : "=v"(wa0) : "v"(p0a[0]), "v"(p0a[1]));
    asm("v_cvt_pk_bf16_f32 %0, %1, %2" : "=v"(wa1) : "v"(p0a[2]), "v"(p0a[3]));
    asm("v_cvt_pk_bf16_f32 %0, %1, %2" : "=v"(wa2) : "v"(p1a[0]), "v"(p1a[1]));
    asm("v_cvt_pk_bf16_f32 %0, %1, %2" : "=v"(wa3) : "v"(p1a[2]), "v"(p1a[3]));
    asm("v_cvt_pk_bf16_f32 %0, %1, %2" : "=v"(wb0) : "v"(p0b[0]), "v"(p0b[1]));
    asm("v_cvt_pk_bf16_f32 %0, %1, %2" : "=v"(wb1) : "v"(p0b[2]), "v"(p0b[3]));
    asm("v_cvt_pk_bf16_f32 %0, %1, %2" : "=v"(wb2) : "v"(p1b[0]), "v"(p1b[1]));
    asm("v_cvt_pk_bf16_f32 %0, %1, %2" : "=v"(wb3) : "v"(p1b[2]), "v"(p1b[3]));
    union { unsigned u[4]; bf16x8 v; } pa, pb;
    pa.u[0] = wa0; pa.u[1] = wa1; pa.u[2] = wa2; pa.u[3] = wa3;
    pb.u[0] = wb0; pb.u[1] = wb1; pb.u[2] = wb2; pb.u[3] = wb3;

    // PV swapped: C[row=d][col=q]; every V-frag read feeds both q-tiles
    int vsw = ((((l15 & 1) << 2) | g) ^ ((l15 >> 1) & 7)) << 4;
    int vbase = (l15 >> 1) * 128 + vsw;
#pragma unroll
    for (int dt = 0; dt < 16; dt++) {
      bf16x8 vf = *(const bf16x8*)(vb + dt * 1024 + vbase);
      acc0[dt] = __builtin_amdgcn_mfma_f32_16x16x32_bf16(vf, pa.v, acc0[dt], 0, 0, 0);
      acc1[dt] = __builtin_amdgcn_mfma_f32_16x16x32_bf16(vf, pb.v, acc1[dt], 0, 0, 0);
    }
  };

  stage(0, smem, smem + 32768);
  __syncthreads();
  for (int t = 0; t < NT; t++) {
    char* kb = smem + (t & 1) * 16384;
    char* vb = smem + 32768 + (t & 1) * 16384;
    if (t + 1 < NT)
      stage(t + 1, smem + ((t + 1) & 1) * 16384, smem + 32768 + ((t + 1) & 1) * 16384);
    step(kb, vb);
    __syncthreads();  // drain lands after compute; 2nd block/CU hides the rest
  }

  // epilogue: both tiles; q lane-local, acc cols=q rows=d
  size_t rowA = (size_t)b * SQL + q0 + l15;
  size_t rowB = rowA + 16;
  if (g == 0) {
    float2 mlA; mlA.x = m0; mlA.y = l0;
    float2 mlB; mlB.x = m1; mlB.y = l1;
    *(float2*)(Ml + ((size_t)sp * NROW + rowA) * 2) = mlA;
    *(float2*)(Ml + ((size_t)sp * NROW + rowB) * 2) = mlB;
  }
  float li0 = 1.0f / l0, li1 = 1.0f / l1;
  unsigned short* oA = Op + ((size_t)sp * NROW + rowA) * HID;
  unsigned short* oB = Op + ((size_t)sp * NROW + rowB) * HID;
#pragma unroll
  for (int dt = 0; dt < 16; dt++) {
    ushort4 v0, v1;
    union { _Float16 hf; unsigned short u; } c;
    c.hf = (_Float16)(acc0[dt][0] * li0); v0.x = c.u;
    c.hf = (_Float16)(acc0[dt][1] * li0); v0.y = c.u;
    c.hf = (_Float16)(acc0[dt][2] * li0); v0.z = c.u;
    c.hf = (_Float16)(acc0[dt][3] * li0); v0.w = c.u;
    c.hf = (_Float16)(acc1[dt][0] * li1); v1.x = c.u;
    c.hf = (_Float16)(acc1[dt][1] * li1); v1.y = c.u;
    c.hf = (_Float16)(acc1[dt][2] * li1); v1.z = c.u;
    c.hf = (_Float16)(acc1[dt][3] * li1); v1.w = c.u;
    *(ushort4*)(oA + dt * 16 + g * 4) = v0;
    *(ushort4*)(oB + dt * 16 + g * 4) = v1;
  }
}

// ---------- C: combine split partials ----------
__global__ __launch_bounds__(256) void comb_kernel(const unsigned short* __restrict__ Op,
                                                   const float* __restrict__ Ml,
                                                   float* __restrict__ out) {
  int idx = blockIdx.x * 256 + threadIdx.x;
  int row = idx >> 6;
  int d0 = (idx & 63) << 2;
  float mv[SPLIT], lv[SPLIT];
#pragma unroll
  for (int s = 0; s < SPLIT; s++) {
    float2 ml = *(const float2*)(Ml + ((size_t)s * NROW + row) * 2);
    mv[s] = ml.x; lv[s] = ml.y;
  }
  float M = mv[0];
#pragma unroll
  for (int s = 1; s < SPLIT; s++) M = fmaxf(M, mv[s]);
  float W = 0.f, w[SPLIT];
#pragma unroll
  for (int s = 0; s < SPLIT; s++) { w[s] = lv[s] * exp2f(mv[s] - M); W += w[s]; }
  float wi = 1.0f / W;
  float o0 = 0.f, o1 = 0.f, o2 = 0.f, o3 = 0.f;
#pragma unroll
  for (int s = 0; s < SPLIT; s++) {
    ushort4 u = *(const ushort4*)(Op + ((size_t)s * NROW + row) * HID + d0);
    union { unsigned short us; _Float16 hf; } c0, c1, c2, c3;
    c0.us = u.x; c1.us = u.y; c2.us = u.z; c3.us = u.w;
    o0 += w[s] * (float)c0.hf; o1 += w[s] * (float)c1.hf;
    o2 += w[s] * (float)c2.hf; o3 += w[s] * (float)c3.hf;
  }
  float4 res; res.x = o0 * wi; res.y = o1 * wi; res.z = o2 * wi; res.w = o3 * wi;
  *(float4*)(out + (size_t)row * HID + d0) = res;
}

extern "C" void kernel_launch(void* const* d_in, const int* in_sizes, int n_in,
                              void* d_out, int out_size, void* d_ws, size_t ws_size,
                              hipStream_t stream) {
  const float* query = (const float*)d_in[0];
  const float* key   = (const float*)d_in[1];
  const float* value = (const float*)d_in[2];
  const float* Wq = (const float*)d_in[3];
  const float* bq = (const float*)d_in[4];
  const float* Wk = (const float*)d_in[5];
  const float* bk = (const float*)d_in[6];
  const float* Wv = (const float*)d_in[7];
  const float* bv = (const float*)d_in[8];

  char* ws = (char*)d_ws;
  unsigned short* Wb  = (unsigned short*)ws;                        // 393216 B
  unsigned short* Qb  = (unsigned short*)(ws + 393216);
  unsigned short* Kb  = Qb + (size_t)NB * SQL * HID;
  unsigned short* Vtb = Kb + (size_t)NB * SKV * HID;                // [b][d][s]
  unsigned short* Op  = Vtb + (size_t)NB * HID * SKV;               // f16 partials
  float* Ml = (float*)(Op + (size_t)SPLIT * NROW * HID);            // (m,l)

  hipLaunchKernelGGL(wconv_kernel, dim3(768), dim3(256), 0, stream, Wq, Wk, Wv, Wb);
  hipLaunchKernelGGL(proj_kernel, dim3(768), dim3(512), 0, stream,
                     query, key, value, Wb, bq, bk, bv, Qb, Kb, Vtb);
  hipLaunchKernelGGL(attn_kernel, dim3(512), dim3(256), 65536, stream, Qb, Kb, Vtb, Op, Ml);
  hipLaunchKernelGGL(comb_kernel, dim3(4096), dim3(256), 0, stream, Op, Ml, (float*)d_out);
}

// Round 9
// 100.043 us; speedup vs baseline: 1.1167x; 1.0378x over previous
//
#include <hip/hip_runtime.h>

#define HID 256
#define NB 8
#define SQL 2048
#define SKV 2048
#define SPLIT 4
#define KPB (SKV / SPLIT)   // 512 keys per (b,split) stream
#define KVB 32              // keys per staged tile
#define NT (KPB / KVB)      // 16 steps
#define NROW (NB * SQL)     // 16384 rows

typedef __attribute__((ext_vector_type(8))) short bf16x8;
typedef __attribute__((ext_vector_type(4))) float f32x4;
typedef __attribute__((ext_vector_type(16))) float f32x16;

static __device__ __forceinline__ unsigned short f2bf(float x) {
  union { float f; unsigned int u; } v; v.f = x;
  unsigned int r = v.u + 0x7FFFu + ((v.u >> 16) & 1u);
  return (unsigned short)(r >> 16);
}

// ---------- P0: convert weight matrices to bf16 ----------
__global__ void wconv_kernel(const float* __restrict__ Wq, const float* __restrict__ Wk,
                             const float* __restrict__ Wv, unsigned short* __restrict__ out) {
  int i = blockIdx.x * blockDim.x + threadIdx.x;
  if (i >= 3 * HID * HID) return;
  const float* src = (i < HID * HID) ? Wq : (i < 2 * HID * HID ? Wk : Wv);
  out[i] = f2bf(src[i & (HID * HID - 1)]);
}

// ---------- P1: QKV projection; W-half staged in LDS (swizzled) ----------
__global__ __launch_bounds__(512, 4) void proj_kernel(
    const float* __restrict__ query, const float* __restrict__ key, const float* __restrict__ value,
    const unsigned short* __restrict__ Wb,
    const float* __restrict__ bq, const float* __restrict__ bk, const float* __restrict__ bv,
    unsigned short* __restrict__ Qb, unsigned short* __restrict__ Kb, unsigned short* __restrict__ Vtb) {
  __shared__ __align__(16) char wl[65536];
  int tid = threadIdx.x;
  int wave = tid >> 6, lane = tid & 63, lr = lane & 15, lg = lane >> 4;
  int blk = blockIdx.x;
  int mat = blk >> 8;       // 0:Q 1:K 2:V
  int rem = blk & 255;
  int b = rem >> 5;
  int rt = (rem >> 1) & 15;
  int et = rem & 1;

  const float* X = (mat == 0) ? query : (mat == 1 ? key : value);
  const float* bias = (mat == 0) ? bq : (mat == 1 ? bk : bv);
  const char* Wsrc = (const char*)(Wb + mat * HID * HID + et * 128 * HID);

#pragma unroll
  for (int i = 0; i < 8; i++) {
    int c = i * 512 + tid;
    int e = c >> 5;
    int glo = e * 512 + (((c & 31) ^ (e & 7)) << 4);
    __builtin_amdgcn_global_load_lds(
        (const __attribute__((address_space(1))) unsigned int*)(Wsrc + glo),
        (__attribute__((address_space(3))) unsigned int*)(wl + c * 16), 16, 0, 0);
  }

  int row_a = rt * 128 + wave * 16 + lr;
  const float* xrow = X + ((size_t)(b * SQL + row_a)) * HID;
  bf16x8 af[8];
#pragma unroll
  for (int s = 0; s < 8; s++) {
    const float4* p = (const float4*)(xrow + s * 32 + lg * 8);
    float4 x0 = p[0], x1 = p[1];
    bf16x8 a;
    a[0] = (short)f2bf(x0.x); a[1] = (short)f2bf(x0.y); a[2] = (short)f2bf(x0.z); a[3] = (short)f2bf(x0.w);
    a[4] = (short)f2bf(x1.x); a[5] = (short)f2bf(x1.y); a[6] = (short)f2bf(x1.z); a[7] = (short)f2bf(x1.w);
    af[s] = a;
  }
  __syncthreads();

  int row_c = rt * 128 + wave * 16 + lg * 4;
#pragma unroll
  for (int eo = 0; eo < 8; eo++) {
    f32x4 acc = (f32x4){0.f, 0.f, 0.f, 0.f};
    int eL = eo * 16 + lr;
#pragma unroll
    for (int sl = 0; sl < 8; sl++) {
      bf16x8 bfr = *(const bf16x8*)(wl + eL * 512 + (((sl * 4 + lg) ^ (eL & 7)) << 4));
      acc = __builtin_amdgcn_mfma_f32_16x16x32_bf16(af[sl], bfr, acc, 0, 0, 0);
    }
    int e = et * 128 + eo * 16 + lr;
    float bv_ = bias[e];
    if (mat < 2) {
      unsigned short* dst = (mat == 0 ? Qb : Kb) + (size_t)(b * SQL) * HID;
#pragma unroll
      for (int i = 0; i < 4; i++)
        dst[(size_t)(row_c + i) * HID + e] = f2bf(acc[i] + bv_);
    } else {
      ushort4 v;
      v.x = f2bf(acc[0] + bv_); v.y = f2bf(acc[1] + bv_);
      v.z = f2bf(acc[2] + bv_); v.w = f2bf(acc[3] + bv_);
      *(ushort4*)(Vtb + ((size_t)(b * HID + e)) * SKV + row_c) = v;
    }
  }
}

// ---------- A: flash attention, deferred-PV pipeline (T15), V tri-buffer ----------
__global__ __launch_bounds__(256, 2) void attn_kernel(
    const unsigned short* __restrict__ Qb, const unsigned short* __restrict__ Kb,
    const unsigned short* __restrict__ Vtb, unsigned short* __restrict__ Op,
    float* __restrict__ Ml) {
  extern __shared__ char smem[];  // K0,K1 (2x16K) @0; V0,V1,V2 (3x16K) @32768
  int tid = threadIdx.x;
  int wave = tid >> 6, lane = tid & 63, l31 = lane & 31, h = lane >> 5;
  int L = (blockIdx.x & 7) * 64 + (blockIdx.x >> 3);  // XCD x owns batch x
  int b = L >> 6, sp = (L >> 4) & 3, qt = L & 15;
  int q0 = qt * 128 + wave * 32;

  const char* Kc0 = (const char*)(Kb + ((size_t)b * SKV + (size_t)sp * KPB) * HID);
  const char* Vc0 = (const char*)(Vtb + (size_t)b * HID * SKV + (size_t)sp * KPB);

  // K LDS (16KB/buf): 32 rows x 512B; slot cs of row ky holds global chunk cs^ky.
  // V LDS (16KB/buf): 128 stripes x 128B; stripe rv slot s holds p=s^(rv&7),
  //                   i.e. d = 2rv+(p>>2), chunk c = p&3 (keys 8c..8c+7).
  int offK[4], offV[4];
#pragma unroll
  for (int i = 0; i < 4; i++) {
    int idx = i * 256 + tid;          // 0..1023 (16B chunks)
    int ky = idx >> 5, cs = idx & 31;
    offK[i] = ky * 512 + ((cs ^ ky) << 4);
    int rv = idx >> 3, pp = idx & 7;
    int p = pp ^ (rv & 7);
    int d = 2 * rv + (p >> 2), c = p & 3;
    offV[i] = d * (SKV * 2) + c * 16;
  }

  auto stage = [&](int t, char* kb, char* vb) {
    const char* Ks = Kc0 + t * (KVB * HID * 2);
    const char* Vs = Vc0 + t * (KVB * 2);
#pragma unroll
    for (int i = 0; i < 4; i++)
      __builtin_amdgcn_global_load_lds(
          (const __attribute__((address_space(1))) unsigned int*)(Ks + offK[i]),
          (__attribute__((address_space(3))) unsigned int*)(kb + (i * 256 + tid) * 16),
          16, 0, 0);
#pragma unroll
    for (int i = 0; i < 4; i++)
      __builtin_amdgcn_global_load_lds(
          (const __attribute__((address_space(1))) unsigned int*)(Vs + offV[i]),
          (__attribute__((address_space(3))) unsigned int*)(vb + (i * 256 + tid) * 16),
          16, 0, 0);
  };

  // Q fragments: lane holds Q[q=l31][s*16 + h*8 ..+7]
  bf16x8 qf[16];
  {
    const unsigned short* qrow = Qb + ((size_t)(b * SQL + q0 + l31)) * HID + h * 8;
#pragma unroll
    for (int s = 0; s < 16; s++) qf[s] = *(const bf16x8*)(qrow + s * 16);
  }

  f32x16 acc[8];
#pragma unroll
  for (int dt = 0; dt < 8; dt++)
#pragma unroll
    for (int j = 0; j < 16; j++) acc[dt][j] = 0.f;

  float m = -1e30f, lsum = 0.f;
  const float kC = 1.44269504088896341f / 11.3137084989847604f;  // log2(e)/sqrt(128)
  bf16x8 pa0, pa1;  // deferred P fragments (tile t-1)

  // QK^T swapped: C[row=key][col=q=l31]
  auto qk = [&](const char* kb) {
    f32x16 p;
#pragma unroll
    for (int j = 0; j < 16; j++) p[j] = 0.f;
#pragma unroll
    for (int s = 0; s < 16; s++) {
      bf16x8 kf = *(const bf16x8*)(kb + l31 * 512 + (((2 * s + h) ^ l31) << 4));
      p = __builtin_amdgcn_mfma_f32_32x32x16_bf16(kf, qf[s], p, 0, 0, 0);
    }
    return p;
  };

  // PV for the previous tile: A = saved P frags, B = V stripes
  auto pv = [&](const char* vb) {
#pragma unroll
    for (int k2 = 0; k2 < 2; k2++) {
      bf16x8 pav = (k2 == 0) ? pa0 : pa1;
#pragma unroll
      for (int dt = 0; dt < 8; dt++) {
        int d = dt * 32 + l31;
        int slot = (((d & 1) * 4 + k2 * 2 + h) ^ ((d >> 1) & 7));
        bf16x8 vf = *(const bf16x8*)(vb + (d >> 1) * 128 + (slot << 4));
        acc[dt] = __builtin_amdgcn_mfma_f32_32x32x16_bf16(pav, vf, acc[dt], 0, 0, 0);
      }
    }
  };

  // softmax for tile t: updates m,l; writes pa0/pa1; rare acc rescale
  auto sm = [&](f32x16 p) {
    float tmax = p[0];
#pragma unroll
    for (int j = 1; j < 16; j++) tmax = fmaxf(tmax, p[j]);
    tmax = fmaxf(tmax, __shfl_xor(tmax, 32, 64));
    float msc = tmax * kC;
    if (!__all(msc <= m + 8.0f)) {     // defer-max THR=8
      float mn = fmaxf(m, msc);
      float al = exp2f(m - mn);
      lsum *= al;
      m = mn;
#pragma unroll
      for (int r = 0; r < 16; r++) {
        int qp = (r & 3) + 8 * (r >> 2) + 4 * h;
        float ar = __shfl(al, qp, 64);
#pragma unroll
        for (int dt = 0; dt < 8; dt++) acc[dt][r] *= ar;
      }
    }
#pragma unroll
    for (int j = 0; j < 16; j++) p[j] = exp2f(fmaf(p[j], kC, -m));
    float ts = 0.f;
#pragma unroll
    for (int j = 0; j < 16; j++) ts += p[j];
    ts += __shfl_xor(ts, 32, 64);
    lsum += ts;

    unsigned P0, P1, P2, P3, P4, P5, P6, P7;
    asm("v_cvt_pk_bf16_f32 %0, %1, %2" : "=v"(P0) : "v"(p[0]), "v"(p[1]));
    asm("v_cvt_pk_bf16_f32 %0, %1, %2" : "=v"(P1) : "v"(p[2]), "v"(p[3]));
    asm("v_cvt_pk_bf16_f32 %0, %1, %2" : "=v"(P2) : "v"(p[4]), "v"(p[5]));
    asm("v_cvt_pk_bf16_f32 %0, %1, %2" : "=v"(P3) : "v"(p[6]), "v"(p[7]));
    asm("v_cvt_pk_bf16_f32 %0, %1, %2" : "=v"(P4) : "v"(p[8]), "v"(p[9]));
    asm("v_cvt_pk_bf16_f32 %0, %1, %2" : "=v"(P5) : "v"(p[10]), "v"(p[11]));
    asm("v_cvt_pk_bf16_f32 %0, %1, %2" : "=v"(P6) : "v"(p[12]), "v"(p[13]));
    asm("v_cvt_pk_bf16_f32 %0, %1, %2" : "=v"(P7) : "v"(p[14]), "v"(p[15]));
    asm("v_permlane32_swap_b32 %0, %1" : "+v"(P0), "+v"(P2));
    asm("v_permlane32_swap_b32 %0, %1" : "+v"(P1), "+v"(P3));
    asm("v_permlane32_swap_b32 %0, %1" : "+v"(P4), "+v"(P6));
    asm("v_permlane32_swap_b32 %0, %1" : "+v"(P5), "+v"(P7));
    union { unsigned u[4]; bf16x8 v; } a0, a1;
    a0.u[0] = P0; a0.u[1] = P1; a0.u[2] = P2; a0.u[3] = P3;
    a1.u[0] = P4; a1.u[1] = P5; a1.u[2] = P6; a1.u[3] = P7;
    pa0 = a0.v; pa1 = a1.v;
  };

  // prologue: tile 0 into K0,V0
  stage(0, smem, smem + 32768);
  __syncthreads();
  // peeled t=0: prefetch 1, QK+SM only
  stage(1, smem + 16384, smem + 32768 + 16384);
  {
    f32x16 p = qk(smem);
    sm(p);
  }
  __syncthreads();

  int vprev = 0, vnext = 2;  // at loop entry t=1: cur buf=1, prev=0, next(t+1=2)%3=2
  for (int t = 1; t < NT; t++) {
    const char* kb = smem + ((t & 1) << 14);
    const char* vbp = smem + 32768 + (vprev << 14);
    if (t + 1 < NT)
      stage(t + 1, smem + (((t + 1) & 1) << 14), smem + 32768 + (vnext << 14));
    f32x16 p = qk(kb);     // MFMA cluster A (tile t)
    pv(vbp);               // MFMA cluster B (tile t-1) — independent, interleaves
    sm(p);                 // VALU chain hides under MFMA issue
    vprev = (vprev == 2) ? 0 : vprev + 1;
    vnext = (vnext == 2) ? 0 : vnext + 1;
    __syncthreads();
  }
  // tail: PV for the last tile
  pv(smem + 32768 + (vprev << 14));

  // epilogue: (m,l) + normalized f16 partial O
  if (h == 0) {
    float2 ml; ml.x = m; ml.y = lsum;
    *(float2*)(Ml + ((size_t)sp * NROW + (size_t)b * SQL + q0 + l31) * 2) = ml;
  }
#pragma unroll
  for (int r = 0; r < 16; r++) {
    int qp = (r & 3) + 8 * (r >> 2) + 4 * h;
    float linv = 1.0f / __shfl(lsum, qp, 64);
    size_t row = (size_t)b * SQL + q0 + qp;
#pragma unroll
    for (int dt = 0; dt < 8; dt++) {
      union { _Float16 hf; unsigned short u; } cv;
      cv.hf = (_Float16)(acc[dt][r] * linv);
      Op[((size_t)sp * NROW + row) * HID + dt * 32 + l31] = cv.u;
    }
  }
}

// ---------- C: combine split partials ----------
__global__ __launch_bounds__(256) void comb_kernel(const unsigned short* __restrict__ Op,
                                                   const float* __restrict__ Ml,
                                                   float* __restrict__ out) {
  int idx = blockIdx.x * 256 + threadIdx.x;
  int row = idx >> 6;
  int d0 = (idx & 63) << 2;
  float mv[SPLIT], lv[SPLIT];
#pragma unroll
  for (int s = 0; s < SPLIT; s++) {
    float2 ml = *(const float2*)(Ml + ((size_t)s * NROW + row) * 2);
    mv[s] = ml.x; lv[s] = ml.y;
  }
  float M = mv[0];
#pragma unroll
  for (int s = 1; s < SPLIT; s++) M = fmaxf(M, mv[s]);
  float W = 0.f, w[SPLIT];
#pragma unroll
  for (int s = 0; s < SPLIT; s++) { w[s] = lv[s] * exp2f(mv[s] - M); W += w[s]; }
  float wi = 1.0f / W;
  float o0 = 0.f, o1 = 0.f, o2 = 0.f, o3 = 0.f;
#pragma unroll
  for (int s = 0; s < SPLIT; s++) {
    ushort4 u = *(const ushort4*)(Op + ((size_t)s * NROW + row) * HID + d0);
    union { unsigned short us; _Float16 hf; } c0, c1, c2, c3;
    c0.us = u.x; c1.us = u.y; c2.us = u.z; c3.us = u.w;
    o0 += w[s] * (float)c0.hf; o1 += w[s] * (float)c1.hf;
    o2 += w[s] * (float)c2.hf; o3 += w[s] * (float)c3.hf;
  }
  float4 res; res.x = o0 * wi; res.y = o1 * wi; res.z = o2 * wi; res.w = o3 * wi;
  *(float4*)(out + (size_t)row * HID + d0) = res;
}

extern "C" void kernel_launch(void* const* d_in, const int* in_sizes, int n_in,
                              void* d_out, int out_size, void* d_ws, size_t ws_size,
                              hipStream_t stream) {
  const float* query = (const float*)d_in[0];
  const float* key   = (const float*)d_in[1];
  const float* value = (const float*)d_in[2];
  const float* Wq = (const float*)d_in[3];
  const float* bq = (const float*)d_in[4];
  const float* Wk = (const float*)d_in[5];
  const float* bk = (const float*)d_in[6];
  const float* Wv = (const float*)d_in[7];
  const float* bv = (const float*)d_in[8];

  char* ws = (char*)d_ws;
  unsigned short* Wb  = (unsigned short*)ws;                        // 393216 B
  unsigned short* Qb  = (unsigned short*)(ws + 393216);
  unsigned short* Kb  = Qb + (size_t)NB * SQL * HID;
  unsigned short* Vtb = Kb + (size_t)NB * SKV * HID;                // [b][d][s]
  unsigned short* Op  = Vtb + (size_t)NB * HID * SKV;               // f16 partials
  float* Ml = (float*)(Op + (size_t)SPLIT * NROW * HID);            // (m,l)

  hipLaunchKernelGGL(wconv_kernel, dim3(768), dim3(256), 0, stream, Wq, Wk, Wv, Wb);
  hipLaunchKernelGGL(proj_kernel, dim3(768), dim3(512), 0, stream,
                     query, key, value, Wb, bq, bk, bv, Qb, Kb, Vtb);
  hipLaunchKernelGGL(attn_kernel, dim3(512), dim3(256), 81920, stream, Qb, Kb, Vtb, Op, Ml);
  hipLaunchKernelGGL(comb_kernel, dim3(4096), dim3(256), 0, stream, Op, Ml, (float*)d_out);
}

// Round 10
// 92.239 us; speedup vs baseline: 1.2112x; 1.0846x over previous
//
#include <hip/hip_runtime.h>

#define HID 256
#define NB 8
#define SQL 2048
#define SKV 2048
#define SPLIT 4
#define KPB (SKV / SPLIT)   // 512 keys per (b,split) stream
#define KVB 32              // keys per staged tile
#define NT (KPB / KVB)      // 16 steps
#define NROW (NB * SQL)     // 16384 rows

typedef __attribute__((ext_vector_type(8))) short bf16x8;
typedef __attribute__((ext_vector_type(4))) float f32x4;

static __device__ __forceinline__ unsigned short f2bf(float x) {
  union { float f; unsigned int u; } v; v.f = x;
  unsigned int r = v.u + 0x7FFFu + ((v.u >> 16) & 1u);
  return (unsigned short)(r >> 16);
}

// ---------- P0: convert weight matrices to bf16 ----------
__global__ void wconv_kernel(const float* __restrict__ Wq, const float* __restrict__ Wk,
                             const float* __restrict__ Wv, unsigned short* __restrict__ out) {
  int i = blockIdx.x * blockDim.x + threadIdx.x;
  if (i >= 3 * HID * HID) return;
  const float* src = (i < HID * HID) ? Wq : (i < 2 * HID * HID ? Wk : Wv);
  out[i] = f2bf(src[i & (HID * HID - 1)]);
}

// ---------- P1: QKV projection; K/V written FRAGMENT-MAJOR ----------
// KF frag(b, tile, half, s): lane(l15,g), j:  K[tile*32 + 8*(l15>>2)+(l15&3)+4*half][s*32+g*8+j]
// VF frag(b, tile, dt):      lane(l15,g), j:  V[tile*32 + g*8 + j][dt*16 + l15]
__global__ __launch_bounds__(512, 4) void proj_kernel(
    const float* __restrict__ query, const float* __restrict__ key, const float* __restrict__ value,
    const unsigned short* __restrict__ Wb,
    const float* __restrict__ bq, const float* __restrict__ bk, const float* __restrict__ bv,
    unsigned short* __restrict__ Qb, unsigned short* __restrict__ KFo, unsigned short* __restrict__ VFo) {
  __shared__ __align__(16) char wl[65536];
  int tid = threadIdx.x;
  int wave = tid >> 6, lane = tid & 63, lr = lane & 15, lg = lane >> 4;
  int blk = blockIdx.x;
  int mat = blk >> 8;       // 0:Q 1:K 2:V
  int rem = blk & 255;
  int b = rem >> 5;
  int rt = (rem >> 1) & 15;
  int et = rem & 1;

  const float* X = (mat == 0) ? query : (mat == 1 ? key : value);
  const float* bias = (mat == 0) ? bq : (mat == 1 ? bk : bv);
  const char* Wsrc = (const char*)(Wb + mat * HID * HID + et * 128 * HID);

#pragma unroll
  for (int i = 0; i < 8; i++) {
    int c = i * 512 + tid;
    int e = c >> 5;
    int glo = e * 512 + (((c & 31) ^ (e & 7)) << 4);
    __builtin_amdgcn_global_load_lds(
        (const __attribute__((address_space(1))) unsigned int*)(Wsrc + glo),
        (__attribute__((address_space(3))) unsigned int*)(wl + c * 16), 16, 0, 0);
  }

  int row_a = rt * 128 + wave * 16 + lr;
  const float* xrow = X + ((size_t)(b * SQL + row_a)) * HID;
  bf16x8 af[8];
#pragma unroll
  for (int s = 0; s < 8; s++) {
    const float4* p = (const float4*)(xrow + s * 32 + lg * 8);
    float4 x0 = p[0], x1 = p[1];
    bf16x8 a;
    a[0] = (short)f2bf(x0.x); a[1] = (short)f2bf(x0.y); a[2] = (short)f2bf(x0.z); a[3] = (short)f2bf(x0.w);
    a[4] = (short)f2bf(x1.x); a[5] = (short)f2bf(x1.y); a[6] = (short)f2bf(x1.z); a[7] = (short)f2bf(x1.w);
    af[s] = a;
  }
  __syncthreads();

  int row_c = rt * 128 + wave * 16 + lg * 4;
#pragma unroll
  for (int eo = 0; eo < 8; eo++) {
    f32x4 acc = (f32x4){0.f, 0.f, 0.f, 0.f};
    int eL = eo * 16 + lr;
#pragma unroll
    for (int sl = 0; sl < 8; sl++) {
      bf16x8 bfr = *(const bf16x8*)(wl + eL * 512 + (((sl * 4 + lg) ^ (eL & 7)) << 4));
      acc = __builtin_amdgcn_mfma_f32_16x16x32_bf16(af[sl], bfr, acc, 0, 0, 0);
    }
    int e = et * 128 + eo * 16 + lr;
    float bv_ = bias[e];
    if (mat == 0) {
      unsigned short* dst = Qb + (size_t)(b * SQL) * HID;
#pragma unroll
      for (int i = 0; i < 4; i++)
        dst[(size_t)(row_c + i) * HID + e] = f2bf(acc[i] + bv_);
    } else if (mat == 1) {
      // scatter into fragment-major KF
      int s = e >> 5, gg = (e >> 3) & 3, j = e & 7;
#pragma unroll
      for (int i = 0; i < 4; i++) {
        int row = row_c + i;
        int k5 = row & 31;
        int half = (k5 >> 2) & 1;
        int lidx = (((k5 >> 3) << 2) | (k5 & 3)) + 16 * gg;
        size_t frag = (size_t)(b * 1024 + (row >> 5) * 16 + half * 8 + s);
        KFo[frag * 512 + lidx * 8 + j] = f2bf(acc[i] + bv_);
      }
    } else {
      // scatter into fragment-major VF
      int dt = e >> 4, l15 = e & 15;
#pragma unroll
      for (int i = 0; i < 4; i++) {
        int row = row_c + i;
        int gg = (row >> 3) & 3, j = row & 7;
        size_t frag = (size_t)(b * 1024 + (row >> 5) * 16 + dt);
        VFo[frag * 512 + (l15 + 16 * gg) * 8 + j] = f2bf(acc[i] + bv_);
      }
    }
  }
}

// ---------- A: flash attention, fragment-major LDS, zero-addressing reads ----------
__global__ __launch_bounds__(256, 2) void attn_kernel(
    const unsigned short* __restrict__ Qb, const char* __restrict__ KF,
    const char* __restrict__ VF, unsigned short* __restrict__ Op,
    float* __restrict__ Ml) {
  extern __shared__ char smem[];  // KA[16K] KB[16K] VA[16K] VB[16K]
  int tid = threadIdx.x;
  int wave = tid >> 6, lane = tid & 63, l15 = lane & 15, g = lane >> 4;
  int L = (blockIdx.x & 7) * 64 + (blockIdx.x >> 3);  // XCD x owns batch x
  int b = L >> 6, sp = (L >> 4) & 3, qt = L & 15;
  int q0 = qt * 128 + wave * 32;   // wave owns q0..q0+31 (2 tiles of 16)

  const char* Ks0 = KF + ((size_t)(b * 64 + sp * 16)) * 16384;
  const char* Vs0 = VF + ((size_t)(b * 64 + sp * 16)) * 16384;

  auto stage = [&](int t, char* kb, char* vb) {
    const char* Ks = Ks0 + (size_t)t * 16384;
    const char* Vs = Vs0 + (size_t)t * 16384;
#pragma unroll
    for (int i = 0; i < 4; i++)
      __builtin_amdgcn_global_load_lds(
          (const __attribute__((address_space(1))) unsigned int*)(Ks + i * 4096 + tid * 16),
          (__attribute__((address_space(3))) unsigned int*)(kb + i * 4096 + tid * 16),
          16, 0, 0);
#pragma unroll
    for (int i = 0; i < 4; i++)
      __builtin_amdgcn_global_load_lds(
          (const __attribute__((address_space(1))) unsigned int*)(Vs + i * 4096 + tid * 16),
          (__attribute__((address_space(3))) unsigned int*)(vb + i * 4096 + tid * 16),
          16, 0, 0);
  };

  // Q fragments for both tiles: lane(q=l15,g) holds Q[q][s*32+g*8..+7]
  bf16x8 qfa[8], qfb[8];
  {
    const unsigned short* qa = Qb + ((size_t)(b * SQL + q0 + l15)) * HID + g * 8;
    const unsigned short* qb2 = qa + 16 * HID;
#pragma unroll
    for (int s = 0; s < 8; s++) {
      qfa[s] = *(const bf16x8*)(qa + s * 32);
      qfb[s] = *(const bf16x8*)(qb2 + s * 32);
    }
  }

  f32x4 acc0[16], acc1[16];  // C[row=d_local=g*4+i][col=q=l15] per d-tile, per q-tile
#pragma unroll
  for (int dt = 0; dt < 16; dt++) {
    acc0[dt] = (f32x4){0.f, 0.f, 0.f, 0.f};
    acc1[dt] = (f32x4){0.f, 0.f, 0.f, 0.f};
  }
  float m0 = -1e30f, l0 = 0.f, m1 = -1e30f, l1 = 0.f;
  const float kC = 1.44269504088896341f / 11.3137084989847604f;  // log2(e)/sqrt(128)

  auto step = [&](const char* kb, const char* vb) {
    const char* kbl = kb + lane * 16;
    const char* vbl = vb + lane * 16;
    // QK^T swapped; frag-major reads: base + imm only
    f32x4 p0a = (f32x4){0.f,0.f,0.f,0.f}, p1a = (f32x4){0.f,0.f,0.f,0.f};
    f32x4 p0b = (f32x4){0.f,0.f,0.f,0.f}, p1b = (f32x4){0.f,0.f,0.f,0.f};
#pragma unroll
    for (int s = 0; s < 8; s++) {
      bf16x8 kf0 = *(const bf16x8*)(kbl + s * 1024);
      bf16x8 kf1 = *(const bf16x8*)(kbl + (8 + s) * 1024);
      p0a = __builtin_amdgcn_mfma_f32_16x16x32_bf16(kf0, qfa[s], p0a, 0, 0, 0);
      p1a = __builtin_amdgcn_mfma_f32_16x16x32_bf16(kf1, qfa[s], p1a, 0, 0, 0);
      p0b = __builtin_amdgcn_mfma_f32_16x16x32_bf16(kf0, qfb[s], p0b, 0, 0, 0);
      p1b = __builtin_amdgcn_mfma_f32_16x16x32_bf16(kf1, qfb[s], p1b, 0, 0, 0);
    }

    // two independent online softmaxes (keys 8g..8g+7 lane-local via sigma in KF)
    float ta = fmaxf(fmaxf(fmaxf(p0a[0], p0a[1]), fmaxf(p0a[2], p0a[3])),
                     fmaxf(fmaxf(p1a[0], p1a[1]), fmaxf(p1a[2], p1a[3])));
    float tb = fmaxf(fmaxf(fmaxf(p0b[0], p0b[1]), fmaxf(p0b[2], p0b[3])),
                     fmaxf(fmaxf(p1b[0], p1b[1]), fmaxf(p1b[2], p1b[3])));
    ta = fmaxf(ta, __shfl_xor(ta, 16, 64)); tb = fmaxf(tb, __shfl_xor(tb, 16, 64));
    ta = fmaxf(ta, __shfl_xor(ta, 32, 64)); tb = fmaxf(tb, __shfl_xor(tb, 32, 64));
    float msa = ta * kC, msb = tb * kC;
    if (!__all(msa <= m0 + 8.0f)) {
      float mn = fmaxf(m0, msa);
      float al = exp2f(m0 - mn);
      l0 *= al; m0 = mn;
#pragma unroll
      for (int dt = 0; dt < 16; dt++)
#pragma unroll
        for (int i = 0; i < 4; i++) acc0[dt][i] *= al;
    }
    if (!__all(msb <= m1 + 8.0f)) {
      float mn = fmaxf(m1, msb);
      float al = exp2f(m1 - mn);
      l1 *= al; m1 = mn;
#pragma unroll
      for (int dt = 0; dt < 16; dt++)
#pragma unroll
        for (int i = 0; i < 4; i++) acc1[dt][i] *= al;
    }
#pragma unroll
    for (int i = 0; i < 4; i++) {
      p0a[i] = exp2f(fmaf(p0a[i], kC, -m0)); p1a[i] = exp2f(fmaf(p1a[i], kC, -m0));
      p0b[i] = exp2f(fmaf(p0b[i], kC, -m1)); p1b[i] = exp2f(fmaf(p1b[i], kC, -m1));
    }
    float sa = (p0a[0] + p0a[1]) + (p0a[2] + p0a[3]) + (p1a[0] + p1a[1]) + (p1a[2] + p1a[3]);
    float sb = (p0b[0] + p0b[1]) + (p0b[2] + p0b[3]) + (p1b[0] + p1b[1]) + (p1b[2] + p1b[3]);
    sa += __shfl_xor(sa, 16, 64); sb += __shfl_xor(sb, 16, 64);
    sa += __shfl_xor(sa, 32, 64); sb += __shfl_xor(sb, 32, 64);
    l0 += sa; l1 += sb;

    // P -> PV B-fragments directly (keys already lane-local)
    unsigned wa0, wa1, wa2, wa3, wb0, wb1, wb2, wb3;
    asm("v_cvt_pk_bf16_f32 %0, %1, %2" : "=v"(wa0) : "v"(p0a[0]), "v"(p0a[1]));
    asm("v_cvt_pk_bf16_f32 %0, %1, %2" : "=v"(wa1) : "v"(p0a[2]), "v"(p0a[3]));
    asm("v_cvt_pk_bf16_f32 %0, %1, %2" : "=v"(wa2) : "v"(p1a[0]), "v"(p1a[1]));
    asm("v_cvt_pk_bf16_f32 %0, %1, %2" : "=v"(wa3) : "v"(p1a[2]), "v"(p1a[3]));
    asm("v_cvt_pk_bf16_f32 %0, %1, %2" : "=v"(wb0) : "v"(p0b[0]), "v"(p0b[1]));
    asm("v_cvt_pk_bf16_f32 %0, %1, %2" : "=v"(wb1) : "v"(p0b[2]), "v"(p0b[3]));
    asm("v_cvt_pk_bf16_f32 %0, %1, %2" : "=v"(wb2) : "v"(p1b[0]), "v"(p1b[1]));
    asm("v_cvt_pk_bf16_f32 %0, %1, %2" : "=v"(wb3) : "v"(p1b[2]), "v"(p1b[3]));
    union { unsigned u[4]; bf16x8 v; } pa, pb;
    pa.u[0] = wa0; pa.u[1] = wa1; pa.u[2] = wa2; pa.u[3] = wa3;
    pb.u[0] = wb0; pb.u[1] = wb1; pb.u[2] = wb2; pb.u[3] = wb3;

    // PV swapped: frag-major V reads (base + imm); each read feeds both q-tiles
#pragma unroll
    for (int dt = 0; dt < 16; dt++) {
      bf16x8 vf = *(const bf16x8*)(vbl + dt * 1024);
      acc0[dt] = __builtin_amdgcn_mfma_f32_16x16x32_bf16(vf, pa.v, acc0[dt], 0, 0, 0);
      acc1[dt] = __builtin_amdgcn_mfma_f32_16x16x32_bf16(vf, pb.v, acc1[dt], 0, 0, 0);
    }
  };

  stage(0, smem, smem + 32768);
  __syncthreads();
  for (int t = 0; t < NT; t++) {
    char* kb = smem + (t & 1) * 16384;
    char* vb = smem + 32768 + (t & 1) * 16384;
    if (t + 1 < NT)
      stage(t + 1, smem + ((t + 1) & 1) * 16384, smem + 32768 + ((t + 1) & 1) * 16384);
    step(kb, vb);
    __syncthreads();  // drain lands after compute; 2nd block/CU hides the rest
  }

  // epilogue: both tiles; q lane-local, acc cols=q rows=d
  size_t rowA = (size_t)b * SQL + q0 + l15;
  size_t rowB = rowA + 16;
  if (g == 0) {
    float2 mlA; mlA.x = m0; mlA.y = l0;
    float2 mlB; mlB.x = m1; mlB.y = l1;
    *(float2*)(Ml + ((size_t)sp * NROW + rowA) * 2) = mlA;
    *(float2*)(Ml + ((size_t)sp * NROW + rowB) * 2) = mlB;
  }
  float li0 = 1.0f / l0, li1 = 1.0f / l1;
  unsigned short* oA = Op + ((size_t)sp * NROW + rowA) * HID;
  unsigned short* oB = Op + ((size_t)sp * NROW + rowB) * HID;
#pragma unroll
  for (int dt = 0; dt < 16; dt++) {
    ushort4 v0, v1;
    union { _Float16 hf; unsigned short u; } c;
    c.hf = (_Float16)(acc0[dt][0] * li0); v0.x = c.u;
    c.hf = (_Float16)(acc0[dt][1] * li0); v0.y = c.u;
    c.hf = (_Float16)(acc0[dt][2] * li0); v0.z = c.u;
    c.hf = (_Float16)(acc0[dt][3] * li0); v0.w = c.u;
    c.hf = (_Float16)(acc1[dt][0] * li1); v1.x = c.u;
    c.hf = (_Float16)(acc1[dt][1] * li1); v1.y = c.u;
    c.hf = (_Float16)(acc1[dt][2] * li1); v1.z = c.u;
    c.hf = (_Float16)(acc1[dt][3] * li1); v1.w = c.u;
    *(ushort4*)(oA + dt * 16 + g * 4) = v0;
    *(ushort4*)(oB + dt * 16 + g * 4) = v1;
  }
}

// ---------- C: combine split partials ----------
__global__ __launch_bounds__(256) void comb_kernel(const unsigned short* __restrict__ Op,
                                                   const float* __restrict__ Ml,
                                                   float* __restrict__ out) {
  int idx = blockIdx.x * 256 + threadIdx.x;
  int row = idx >> 6;
  int d0 = (idx & 63) << 2;
  float mv[SPLIT], lv[SPLIT];
#pragma unroll
  for (int s = 0; s < SPLIT; s++) {
    float2 ml = *(const float2*)(Ml + ((size_t)s * NROW + row) * 2);
    mv[s] = ml.x; lv[s] = ml.y;
  }
  float M = mv[0];
#pragma unroll
  for (int s = 1; s < SPLIT; s++) M = fmaxf(M, mv[s]);
  float W = 0.f, w[SPLIT];
#pragma unroll
  for (int s = 0; s < SPLIT; s++) { w[s] = lv[s] * exp2f(mv[s] - M); W += w[s]; }
  float wi = 1.0f / W;
  float o0 = 0.f, o1 = 0.f, o2 = 0.f, o3 = 0.f;
#pragma unroll
  for (int s = 0; s < SPLIT; s++) {
    ushort4 u = *(const ushort4*)(Op + ((size_t)s * NROW + row) * HID + d0);
    union { unsigned short us; _Float16 hf; } c0, c1, c2, c3;
    c0.us = u.x; c1.us = u.y; c2.us = u.z; c3.us = u.w;
    o0 += w[s] * (float)c0.hf; o1 += w[s] * (float)c1.hf;
    o2 += w[s] * (float)c2.hf; o3 += w[s] * (float)c3.hf;
  }
  float4 res; res.x = o0 * wi; res.y = o1 * wi; res.z = o2 * wi; res.w = o3 * wi;
  *(float4*)(out + (size_t)row * HID + d0) = res;
}

extern "C" void kernel_launch(void* const* d_in, const int* in_sizes, int n_in,
                              void* d_out, int out_size, void* d_ws, size_t ws_size,
                              hipStream_t stream) {
  const float* query = (const float*)d_in[0];
  const float* key   = (const float*)d_in[1];
  const float* value = (const float*)d_in[2];
  const float* Wq = (const float*)d_in[3];
  const float* bq = (const float*)d_in[4];
  const float* Wk = (const float*)d_in[5];
  const float* bk = (const float*)d_in[6];
  const float* Wv = (const float*)d_in[7];
  const float* bv = (const float*)d_in[8];

  char* ws = (char*)d_ws;
  unsigned short* Wb  = (unsigned short*)ws;                        // 393216 B
  unsigned short* Qb  = (unsigned short*)(ws + 393216);
  unsigned short* KF  = Qb + (size_t)NB * SQL * HID;                // fragment-major K
  unsigned short* VF  = KF + (size_t)NB * SKV * HID;                // fragment-major V
  unsigned short* Op  = VF + (size_t)NB * HID * SKV;                // f16 partials
  float* Ml = (float*)(Op + (size_t)SPLIT * NROW * HID);            // (m,l)

  hipLaunchKernelGGL(wconv_kernel, dim3(768), dim3(256), 0, stream, Wq, Wk, Wv, Wb);
  hipLaunchKernelGGL(proj_kernel, dim3(768), dim3(512), 0, stream,
                     query, key, value, Wb, bq, bk, bv, Qb, KF, VF);
  hipLaunchKernelGGL(attn_kernel, dim3(512), dim3(256), 65536, stream,
                     Qb, (const char*)KF, (const char*)VF, Op, Ml);
  hipLaunchKernelGGL(comb_kernel, dim3(4096), dim3(256), 0, stream, Op, Ml, (float*)d_out);
}